// Round 1
// baseline (1826.202 us; speedup 1.0000x reference)
//
#include <hip/hip_runtime.h>
#include <hip/hip_bf16.h>

#define NN 50000
#define NE 800000
#define HID 128
#define NG 256
#define NC 10

// ---------------------------------------------------------------------------
// dual GEMM: xl = in @ Wl, xr = in @ Wr.  in:[n,128], W:[128,128] row-major.
// 64-node tile staged in LDS; 512 threads; thread = 4 cols x 8 nodes.
// Within a wave: lanes share the node group (LDS reads broadcast), cols are
// consecutive (W loads coalesced).
// ---------------------------------------------------------------------------
__global__ __launch_bounds__(512) void k_dual_gemm(
    const float* __restrict__ in, const float* __restrict__ Wl,
    const float* __restrict__ Wr, float* __restrict__ xl,
    float* __restrict__ xr, int n)
{
    __shared__ float xs[64 * 128];
    const int tile = blockIdx.x;
    const int t = threadIdx.x;

    // stage 64x128 input tile (coalesced float4)
    for (int f = t * 4; f < 64 * 128; f += 512 * 4) {
        int node = tile * 64 + (f >> 7);
        float4 v = make_float4(0.f, 0.f, 0.f, 0.f);
        if (node < n) v = *(const float4*)(in + (size_t)tile * 8192 + f);
        *(float4*)(xs + f) = v;
    }
    __syncthreads();

    const int cg = t & 63;        // column group: 4 consecutive cols
    const int ng = t >> 6;        // node group: 8 consecutive nodes
    const int c0 = cg * 4;
    const float* Wp = (c0 < 128) ? (Wl + c0) : (Wr + (c0 - 128));
    float* Op = (c0 < 128) ? xl : xr;
    const int co = c0 & 127;
    const float* xrow = xs + ng * 8 * 128;

    float4 acc[8];
#pragma unroll
    for (int i = 0; i < 8; i++) acc[i] = make_float4(0.f, 0.f, 0.f, 0.f);

    for (int k0 = 0; k0 < 128; k0 += 4) {
        float4 w0 = *(const float4*)(Wp + (size_t)(k0 + 0) * 128);
        float4 w1 = *(const float4*)(Wp + (size_t)(k0 + 1) * 128);
        float4 w2 = *(const float4*)(Wp + (size_t)(k0 + 2) * 128);
        float4 w3 = *(const float4*)(Wp + (size_t)(k0 + 3) * 128);
#pragma unroll
        for (int i = 0; i < 8; i++) {
            float4 xv = *(const float4*)(xrow + i * 128 + k0);
            acc[i].x = fmaf(xv.x, w0.x, acc[i].x);
            acc[i].y = fmaf(xv.x, w0.y, acc[i].y);
            acc[i].z = fmaf(xv.x, w0.z, acc[i].z);
            acc[i].w = fmaf(xv.x, w0.w, acc[i].w);
            acc[i].x = fmaf(xv.y, w1.x, acc[i].x);
            acc[i].y = fmaf(xv.y, w1.y, acc[i].y);
            acc[i].z = fmaf(xv.y, w1.z, acc[i].z);
            acc[i].w = fmaf(xv.y, w1.w, acc[i].w);
            acc[i].x = fmaf(xv.z, w2.x, acc[i].x);
            acc[i].y = fmaf(xv.z, w2.y, acc[i].y);
            acc[i].z = fmaf(xv.z, w2.z, acc[i].z);
            acc[i].w = fmaf(xv.z, w2.w, acc[i].w);
            acc[i].x = fmaf(xv.w, w3.x, acc[i].x);
            acc[i].y = fmaf(xv.w, w3.y, acc[i].y);
            acc[i].z = fmaf(xv.w, w3.z, acc[i].z);
            acc[i].w = fmaf(xv.w, w3.w, acc[i].w);
        }
    }

#pragma unroll
    for (int i = 0; i < 8; i++) {
        int node = tile * 64 + ng * 8 + i;
        if (node < n) *(float4*)(Op + (size_t)node * 128 + co) = acc[i];
    }
}

// ---------------------------------------------------------------------------
// Edge pass: one wave per edge (incl. self-loops at the tail).
// e = dot(leaky_relu(xl[src]+xr[dst]), att); p = exp(e);
// den[dst] += p; acc[dst][:] += p * xl[src][:]
// (max-subtraction skipped: mathematically cancels, e ~ N(0,1) here)
// ---------------------------------------------------------------------------
__global__ __launch_bounds__(256) void k_edge(
    const float* __restrict__ xl, const float* __restrict__ xr,
    const float* __restrict__ att, const int* __restrict__ ei,
    float* __restrict__ acc, float* __restrict__ den, int ntot)
{
    int gw = (int)((blockIdx.x * 256 + threadIdx.x) >> 6);
    int lane = threadIdx.x & 63;
    if (gw >= ntot) return;

    int s, d;
    if (gw < NE) { s = ei[gw]; d = ei[NE + gw]; }
    else         { s = gw - NE; d = s; }

    float2 a = *(const float2*)(xl + (size_t)s * 128 + lane * 2);
    float2 b = *(const float2*)(xr + (size_t)d * 128 + lane * 2);
    float vx = a.x + b.x, vy = a.y + b.y;
    vx = vx > 0.f ? vx : 0.2f * vx;
    vy = vy > 0.f ? vy : 0.2f * vy;
    float2 at = *(const float2*)(att + lane * 2);
    float e = vx * at.x + vy * at.y;
#pragma unroll
    for (int off = 32; off; off >>= 1) e += __shfl_xor(e, off, 64);

    float p = __expf(fminf(e, 80.f));
    if (lane == 0) atomicAdd(den + d, p);
    atomicAdd(acc + (size_t)d * 128 + lane * 2,     p * a.x);
    atomicAdd(acc + (size_t)d * 128 + lane * 2 + 1, p * a.y);
}

// ---------------------------------------------------------------------------
// finalize layer1: h = LN(relu(acc/den + b1)) * g + b   (wave per node)
// ---------------------------------------------------------------------------
__global__ __launch_bounds__(256) void k_fin1(
    const float* __restrict__ acc, const float* __restrict__ den,
    const float* __restrict__ bias, const float* __restrict__ g_ln,
    const float* __restrict__ b_ln, float* __restrict__ h)
{
    int i = (int)((blockIdx.x * 256 + threadIdx.x) >> 6);
    int lane = threadIdx.x & 63;
    if (i >= NN) return;

    float inv = 1.f / (den[i] + 1e-16f);
    float2 v = *(const float2*)(acc + (size_t)i * 128 + lane * 2);
    float2 bb = *(const float2*)(bias + lane * 2);
    float x0 = fmaxf(fmaf(v.x, inv, bb.x), 0.f);
    float x1 = fmaxf(fmaf(v.y, inv, bb.y), 0.f);

    float s1 = x0 + x1, s2 = x0 * x0 + x1 * x1;
#pragma unroll
    for (int off = 32; off; off >>= 1) {
        s1 += __shfl_xor(s1, off, 64);
        s2 += __shfl_xor(s2, off, 64);
    }
    float mu = s1 * (1.f / 128.f);
    float var = s2 * (1.f / 128.f) - mu * mu;
    float rstd = rsqrtf(var + 1e-5f);

    float2 g = *(const float2*)(g_ln + lane * 2);
    float2 bl = *(const float2*)(b_ln + lane * 2);
    float2 o;
    o.x = (x0 - mu) * rstd * g.x + bl.x;
    o.y = (x1 - mu) * rstd * g.y + bl.y;
    *(float2*)(h + (size_t)i * 128 + lane * 2) = o;
}

// ---------------------------------------------------------------------------
// finalize layer2 + mean-pool scatter: o = acc/den + b2; pooled[batch[i]] += o
// ---------------------------------------------------------------------------
__global__ __launch_bounds__(256) void k_fin2_pool(
    const float* __restrict__ acc, const float* __restrict__ den,
    const float* __restrict__ bias, const int* __restrict__ batch,
    float* __restrict__ pooled, float* __restrict__ cnt)
{
    int i = (int)((blockIdx.x * 256 + threadIdx.x) >> 6);
    int lane = threadIdx.x & 63;
    if (i >= NN) return;

    float inv = 1.f / (den[i] + 1e-16f);
    float2 v = *(const float2*)(acc + (size_t)i * 128 + lane * 2);
    float2 bb = *(const float2*)(bias + lane * 2);
    float o0 = fmaf(v.x, inv, bb.x);
    float o1 = fmaf(v.y, inv, bb.y);

    int g = batch[i];
    atomicAdd(pooled + (size_t)g * 128 + lane * 2,     o0);
    atomicAdd(pooled + (size_t)g * 128 + lane * 2 + 1, o1);
    if (lane == 0) atomicAdd(cnt + g, 1.f);
}

// ---------------------------------------------------------------------------
// final linear: out[g][c] = (sum_k pooled[g][k]*W[k][c]) / cnt[g] + b[c]
// ---------------------------------------------------------------------------
__global__ __launch_bounds__(256) void k_linear(
    const float* __restrict__ pooled, const float* __restrict__ cnt,
    const float* __restrict__ W, const float* __restrict__ b,
    float* __restrict__ out)
{
    int idx = blockIdx.x * 256 + threadIdx.x;
    if (idx >= NG * NC) return;
    int g = idx / NC, c = idx % NC;
    float invc = 1.f / fmaxf(cnt[g], 1.f);
    float s = 0.f;
    for (int k = 0; k < HID; k++)
        s = fmaf(pooled[(size_t)g * 128 + k], W[(size_t)k * NC + c], s);
    out[idx] = fmaf(s, invc, b[c]);
}

// ---------------------------------------------------------------------------
extern "C" void kernel_launch(void* const* d_in, const int* in_sizes, int n_in,
                              void* d_out, int out_size, void* d_ws, size_t ws_size,
                              hipStream_t stream)
{
    const float* x     = (const float*)d_in[0];
    const int*   ei    = (const int*)d_in[1];
    const int*   batch = (const int*)d_in[2];
    const float* Wl1   = (const float*)d_in[3];
    const float* Wr1   = (const float*)d_in[4];
    const float* att1  = (const float*)d_in[5];
    const float* b1    = (const float*)d_in[6];
    const float* g_ln  = (const float*)d_in[7];
    const float* b_ln  = (const float*)d_in[8];
    const float* Wl2   = (const float*)d_in[9];
    const float* Wr2   = (const float*)d_in[10];
    const float* att2  = (const float*)d_in[11];
    const float* b2    = (const float*)d_in[12];
    const float* Wlin  = (const float*)d_in[13];
    const float* blin  = (const float*)d_in[14];
    float* out = (float*)d_out;

    float* ws = (float*)d_ws;
    float* xl     = ws;                     // 6.4M floats
    float* xr     = xl + (size_t)NN * HID;  // 6.4M
    float* h      = xr + (size_t)NN * HID;  // 6.4M
    float* acc    = h  + (size_t)NN * HID;  // 6.4M
    float* den    = acc + (size_t)NN * HID; // 50000
    float* pooled = den + NN;               // 32768
    float* cnt    = pooled + (size_t)NG * HID; // 256

    const int ETOT = NE + NN;               // 850000 edges incl. self-loops
    const int edge_blocks = ETOT / 4;       // 1 wave per edge, 4 waves/block
    const int node_blocks = (NN + 3) / 4;
    const int gemm_blocks = (NN + 63) / 64;

    // zero accumulators (acc+den contiguous; pooled+cnt contiguous)
    hipMemsetAsync(acc, 0, ((size_t)NN * HID + NN) * sizeof(float), stream);
    hipMemsetAsync(pooled, 0, ((size_t)NG * HID + NG) * sizeof(float), stream);

    // ---- layer 1 ----
    k_dual_gemm<<<gemm_blocks, 512, 0, stream>>>(x, Wl1, Wr1, xl, xr, NN);
    k_edge<<<edge_blocks, 256, 0, stream>>>(xl, xr, att1, ei, acc, den, ETOT);
    k_fin1<<<node_blocks, 256, 0, stream>>>(acc, den, b1, g_ln, b_ln, h);

    // ---- layer 2 ----
    hipMemsetAsync(acc, 0, ((size_t)NN * HID + NN) * sizeof(float), stream);
    k_dual_gemm<<<gemm_blocks, 512, 0, stream>>>(h, Wl2, Wr2, xl, xr, NN);
    k_edge<<<edge_blocks, 256, 0, stream>>>(xl, xr, att2, ei, acc, den, ETOT);
    k_fin2_pool<<<node_blocks, 256, 0, stream>>>(acc, den, b2, batch, pooled, cnt);

    // ---- head ----
    k_linear<<<(NG * NC + 255) / 256, 256, 0, stream>>>(pooled, cnt, Wlin, blin, out);
}

// Round 2
// 612.407 us; speedup vs baseline: 2.9820x; 2.9820x over previous
//
#include <hip/hip_runtime.h>
#include <hip/hip_bf16.h>

#define NN 50000
#define NE 800000
#define HID 128
#define NG 256
#define NC 10

// ---------------------------------------------------------------------------
// dual GEMM: xl = in @ Wl, xr = in @ Wr.  in:[n,128], W:[128,128] row-major.
// 64-node tile staged in LDS; 512 threads; thread = 4 cols x 8 nodes.
// ---------------------------------------------------------------------------
__global__ __launch_bounds__(512) void k_dual_gemm(
    const float* __restrict__ in, const float* __restrict__ Wl,
    const float* __restrict__ Wr, float* __restrict__ xl,
    float* __restrict__ xr, int n)
{
    __shared__ float xs[64 * 128];
    const int tile = blockIdx.x;
    const int t = threadIdx.x;

    for (int f = t * 4; f < 64 * 128; f += 512 * 4) {
        int node = tile * 64 + (f >> 7);
        float4 v = make_float4(0.f, 0.f, 0.f, 0.f);
        if (node < n) v = *(const float4*)(in + (size_t)tile * 8192 + f);
        *(float4*)(xs + f) = v;
    }
    __syncthreads();

    const int cg = t & 63;
    const int ng = t >> 6;
    const int c0 = cg * 4;
    const float* Wp = (c0 < 128) ? (Wl + c0) : (Wr + (c0 - 128));
    float* Op = (c0 < 128) ? xl : xr;
    const int co = c0 & 127;
    const float* xrow = xs + ng * 8 * 128;

    float4 acc[8];
#pragma unroll
    for (int i = 0; i < 8; i++) acc[i] = make_float4(0.f, 0.f, 0.f, 0.f);

    for (int k0 = 0; k0 < 128; k0 += 4) {
        float4 w0 = *(const float4*)(Wp + (size_t)(k0 + 0) * 128);
        float4 w1 = *(const float4*)(Wp + (size_t)(k0 + 1) * 128);
        float4 w2 = *(const float4*)(Wp + (size_t)(k0 + 2) * 128);
        float4 w3 = *(const float4*)(Wp + (size_t)(k0 + 3) * 128);
#pragma unroll
        for (int i = 0; i < 8; i++) {
            float4 xv = *(const float4*)(xrow + i * 128 + k0);
            acc[i].x = fmaf(xv.x, w0.x, acc[i].x);
            acc[i].y = fmaf(xv.x, w0.y, acc[i].y);
            acc[i].z = fmaf(xv.x, w0.z, acc[i].z);
            acc[i].w = fmaf(xv.x, w0.w, acc[i].w);
            acc[i].x = fmaf(xv.y, w1.x, acc[i].x);
            acc[i].y = fmaf(xv.y, w1.y, acc[i].y);
            acc[i].z = fmaf(xv.y, w1.z, acc[i].z);
            acc[i].w = fmaf(xv.y, w1.w, acc[i].w);
            acc[i].x = fmaf(xv.z, w2.x, acc[i].x);
            acc[i].y = fmaf(xv.z, w2.y, acc[i].y);
            acc[i].z = fmaf(xv.z, w2.z, acc[i].z);
            acc[i].w = fmaf(xv.z, w2.w, acc[i].w);
            acc[i].x = fmaf(xv.w, w3.x, acc[i].x);
            acc[i].y = fmaf(xv.w, w3.y, acc[i].y);
            acc[i].z = fmaf(xv.w, w3.z, acc[i].z);
            acc[i].w = fmaf(xv.w, w3.w, acc[i].w);
        }
    }

#pragma unroll
    for (int i = 0; i < 8; i++) {
        int node = tile * 64 + ng * 8 + i;
        if (node < n) *(float4*)(Op + (size_t)node * 128 + co) = acc[i];
    }
}

// ---------------------------------------------------------------------------
// CSR build (dst-sorted), done once per call, reused by both layers.
// Self-loop for node d occupies slot rowptr[d]; real edges follow.
// ---------------------------------------------------------------------------
__global__ __launch_bounds__(256) void k_deg_init(int* __restrict__ deg)
{
    int i = blockIdx.x * 256 + threadIdx.x;
    if (i < NN) deg[i] = 1;  // self-loop
}

__global__ __launch_bounds__(256) void k_hist(
    const int* __restrict__ ei, int* __restrict__ deg)
{
    int e = blockIdx.x * 256 + threadIdx.x;
    if (e < NE) atomicAdd(deg + ei[NE + e], 1);
}

__global__ __launch_bounds__(1024) void k_scan(
    const int* __restrict__ deg, int* __restrict__ rowptr)
{
    __shared__ int ps[1024];
    const int t = threadIdx.x;
    const int CH = 49;  // 1024*49 >= 50000
    int lo = t * CH, hi = min(lo + CH, NN);
    int s = 0;
    for (int i = lo; i < hi; i++) s += deg[i];
    ps[t] = s;
    __syncthreads();
    for (int off = 1; off < 1024; off <<= 1) {
        int v = (t >= off) ? ps[t - off] : 0;
        __syncthreads();
        ps[t] += v;
        __syncthreads();
    }
    int base = (t == 0) ? 0 : ps[t - 1];
    for (int i = lo; i < hi; i++) { rowptr[i] = base; base += deg[i]; }
    if (t == 0) rowptr[NN] = NE + NN;
}

__global__ __launch_bounds__(256) void k_fill_self(
    const int* __restrict__ rowptr, int* __restrict__ nxt,
    int* __restrict__ esrc)
{
    int i = blockIdx.x * 256 + threadIdx.x;
    if (i >= NN) return;
    int r = rowptr[i];
    esrc[r] = i;
    nxt[i] = r + 1;
}

__global__ __launch_bounds__(256) void k_scatter(
    const int* __restrict__ ei, int* __restrict__ nxt,
    int* __restrict__ esrc)
{
    int e = blockIdx.x * 256 + threadIdx.x;
    if (e >= NE) return;
    int s = ei[e], d = ei[NE + e];
    int pos = atomicAdd(nxt + d, 1);
    esrc[pos] = s;
}

// ---------------------------------------------------------------------------
// Gather-based GAT row: half-wave (32 lanes x float4 = 128 feats) per dst.
// Returns un-normalized acc and denominator in registers.
// ---------------------------------------------------------------------------
__device__ __forceinline__ void gat_row(
    const float* __restrict__ xl, const float4 xr4, const float4 at,
    const int* __restrict__ esrc, int beg, int end, int q,
    float4& acc, float& den)
{
    acc = make_float4(0.f, 0.f, 0.f, 0.f);
    den = 0.f;
    int idx = beg;
    int s = esrc[idx];
    float4 a = *(const float4*)(xl + (size_t)s * 128 + q * 4);
    while (idx < end) {
        float4 cur = a;
        ++idx;
        if (idx < end) {  // prefetch next edge
            s = esrc[idx];
            a = *(const float4*)(xl + (size_t)s * 128 + q * 4);
        }
        float v0 = cur.x + xr4.x; v0 = v0 > 0.f ? v0 : 0.2f * v0;
        float v1 = cur.y + xr4.y; v1 = v1 > 0.f ? v1 : 0.2f * v1;
        float v2 = cur.z + xr4.z; v2 = v2 > 0.f ? v2 : 0.2f * v2;
        float v3 = cur.w + xr4.w; v3 = v3 > 0.f ? v3 : 0.2f * v3;
        float e = v0 * at.x + v1 * at.y + v2 * at.z + v3 * at.w;
#pragma unroll
        for (int off = 16; off; off >>= 1) e += __shfl_xor(e, off, 64);
        float p = __expf(fminf(e, 80.f));
        den += p;
        acc.x = fmaf(p, cur.x, acc.x);
        acc.y = fmaf(p, cur.y, acc.y);
        acc.z = fmaf(p, cur.z, acc.z);
        acc.w = fmaf(p, cur.w, acc.w);
    }
}

// layer1: fused normalize + bias + ReLU + LayerNorm -> h
__global__ __launch_bounds__(256) void k_gat1(
    const float* __restrict__ xl, const float* __restrict__ xr,
    const float* __restrict__ att, const int* __restrict__ rowptr,
    const int* __restrict__ esrc, const float* __restrict__ bias,
    const float* __restrict__ g_ln, const float* __restrict__ b_ln,
    float* __restrict__ h)
{
    int d = (int)((blockIdx.x * 256 + threadIdx.x) >> 5);
    int q = threadIdx.x & 31;
    if (d >= NN) return;

    float4 xr4 = *(const float4*)(xr + (size_t)d * 128 + q * 4);
    float4 at  = *(const float4*)(att + q * 4);
    float4 acc; float den;
    gat_row(xl, xr4, at, esrc, rowptr[d], rowptr[d + 1], q, acc, den);

    float inv = 1.f / (den + 1e-16f);
    float4 bb = *(const float4*)(bias + q * 4);
    float x0 = fmaxf(fmaf(acc.x, inv, bb.x), 0.f);
    float x1 = fmaxf(fmaf(acc.y, inv, bb.y), 0.f);
    float x2 = fmaxf(fmaf(acc.z, inv, bb.z), 0.f);
    float x3 = fmaxf(fmaf(acc.w, inv, bb.w), 0.f);

    float s1 = x0 + x1 + x2 + x3;
    float s2 = x0 * x0 + x1 * x1 + x2 * x2 + x3 * x3;
#pragma unroll
    for (int off = 16; off; off >>= 1) {
        s1 += __shfl_xor(s1, off, 64);
        s2 += __shfl_xor(s2, off, 64);
    }
    float mu = s1 * (1.f / 128.f);
    float var = s2 * (1.f / 128.f) - mu * mu;
    float rstd = rsqrtf(var + 1e-5f);

    float4 g  = *(const float4*)(g_ln + q * 4);
    float4 bl = *(const float4*)(b_ln + q * 4);
    float4 o;
    o.x = (x0 - mu) * rstd * g.x + bl.x;
    o.y = (x1 - mu) * rstd * g.y + bl.y;
    o.z = (x2 - mu) * rstd * g.z + bl.z;
    o.w = (x3 - mu) * rstd * g.w + bl.w;
    *(float4*)(h + (size_t)d * 128 + q * 4) = o;
}

// layer2: fused normalize + bias + mean-pool scatter
__global__ __launch_bounds__(256) void k_gat2(
    const float* __restrict__ xl, const float* __restrict__ xr,
    const float* __restrict__ att, const int* __restrict__ rowptr,
    const int* __restrict__ esrc, const float* __restrict__ bias,
    const int* __restrict__ batch, float* __restrict__ pooled,
    float* __restrict__ cnt)
{
    int d = (int)((blockIdx.x * 256 + threadIdx.x) >> 5);
    int q = threadIdx.x & 31;
    if (d >= NN) return;

    float4 xr4 = *(const float4*)(xr + (size_t)d * 128 + q * 4);
    float4 at  = *(const float4*)(att + q * 4);
    float4 acc; float den;
    gat_row(xl, xr4, at, esrc, rowptr[d], rowptr[d + 1], q, acc, den);

    float inv = 1.f / (den + 1e-16f);
    float4 bb = *(const float4*)(bias + q * 4);
    int g = batch[d];
    float* pp = pooled + (size_t)g * 128 + q * 4;
    atomicAdd(pp + 0, fmaf(acc.x, inv, bb.x));
    atomicAdd(pp + 1, fmaf(acc.y, inv, bb.y));
    atomicAdd(pp + 2, fmaf(acc.z, inv, bb.z));
    atomicAdd(pp + 3, fmaf(acc.w, inv, bb.w));
    if (q == 0) atomicAdd(cnt + g, 1.f);
}

// ---------------------------------------------------------------------------
__global__ __launch_bounds__(256) void k_linear(
    const float* __restrict__ pooled, const float* __restrict__ cnt,
    const float* __restrict__ W, const float* __restrict__ b,
    float* __restrict__ out)
{
    int idx = blockIdx.x * 256 + threadIdx.x;
    if (idx >= NG * NC) return;
    int g = idx / NC, c = idx % NC;
    float invc = 1.f / fmaxf(cnt[g], 1.f);
    float s = 0.f;
    for (int k = 0; k < HID; k++)
        s = fmaf(pooled[(size_t)g * 128 + k], W[(size_t)k * NC + c], s);
    out[idx] = fmaf(s, invc, b[c]);
}

// ---------------------------------------------------------------------------
extern "C" void kernel_launch(void* const* d_in, const int* in_sizes, int n_in,
                              void* d_out, int out_size, void* d_ws, size_t ws_size,
                              hipStream_t stream)
{
    const float* x     = (const float*)d_in[0];
    const int*   ei    = (const int*)d_in[1];
    const int*   batch = (const int*)d_in[2];
    const float* Wl1   = (const float*)d_in[3];
    const float* Wr1   = (const float*)d_in[4];
    const float* att1  = (const float*)d_in[5];
    const float* b1    = (const float*)d_in[6];
    const float* g_ln  = (const float*)d_in[7];
    const float* b_ln  = (const float*)d_in[8];
    const float* Wl2   = (const float*)d_in[9];
    const float* Wr2   = (const float*)d_in[10];
    const float* att2  = (const float*)d_in[11];
    const float* b2    = (const float*)d_in[12];
    const float* Wlin  = (const float*)d_in[13];
    const float* blin  = (const float*)d_in[14];
    float* out = (float*)d_out;

    float* ws = (float*)d_ws;
    float* xl     = ws;                           // 6.4M floats
    float* xr     = xl + (size_t)NN * HID;        // 6.4M
    float* h      = xr + (size_t)NN * HID;        // 6.4M
    float* pooled = h + (size_t)NN * HID;         // 32768
    float* cnt    = pooled + (size_t)NG * HID;    // 256
    int* deg    = (int*)(cnt + NG);               // NN
    int* rowptr = deg + NN;                       // NN+1
    int* nxt    = rowptr + NN + 1;                // NN
    int* esrc   = nxt + NN;                       // NE+NN

    const int node_blocks = (NN + 255) / 256;
    const int edge_blocks = (NE + 255) / 256;
    const int gemm_blocks = (NN + 63) / 64;
    const int gat_blocks  = (NN * 32 + 255) / 256;  // half-wave per node

    // ---- CSR build (once; shared by both layers) ----
    k_deg_init<<<node_blocks, 256, 0, stream>>>(deg);
    k_hist<<<edge_blocks, 256, 0, stream>>>(ei, deg);
    k_scan<<<1, 1024, 0, stream>>>(deg, rowptr);
    k_fill_self<<<node_blocks, 256, 0, stream>>>(rowptr, nxt, esrc);
    k_scatter<<<edge_blocks, 256, 0, stream>>>(ei, nxt, esrc);

    hipMemsetAsync(pooled, 0, ((size_t)NG * HID + NG) * sizeof(float), stream);

    // ---- layer 1 ----
    k_dual_gemm<<<gemm_blocks, 512, 0, stream>>>(x, Wl1, Wr1, xl, xr, NN);
    k_gat1<<<gat_blocks, 256, 0, stream>>>(xl, xr, att1, rowptr, esrc,
                                           b1, g_ln, b_ln, h);

    // ---- layer 2 ----
    k_dual_gemm<<<gemm_blocks, 512, 0, stream>>>(h, Wl2, Wr2, xl, xr, NN);
    k_gat2<<<gat_blocks, 256, 0, stream>>>(xl, xr, att2, rowptr, esrc,
                                           b2, batch, pooled, cnt);

    // ---- head ----
    k_linear<<<(NG * NC + 255) / 256, 256, 0, stream>>>(pooled, cnt, Wlin, blin, out);
}

// Round 3
// 596.669 us; speedup vs baseline: 3.0607x; 1.0264x over previous
//
#include <hip/hip_runtime.h>
#include <hip/hip_bf16.h>

#define NN 50000
#define NE 800000
#define HID 128
#define NG 256
#define NC 10

// ---------------------------------------------------------------------------
// dual GEMM: xl = in @ Wl, xr = in @ Wr.  in:[n,128], W:[128,128] row-major.
// ---------------------------------------------------------------------------
__global__ __launch_bounds__(512) void k_dual_gemm(
    const float* __restrict__ in, const float* __restrict__ Wl,
    const float* __restrict__ Wr, float* __restrict__ xl,
    float* __restrict__ xr, int n)
{
    __shared__ float xs[64 * 128];
    const int tile = blockIdx.x;
    const int t = threadIdx.x;

    for (int f = t * 4; f < 64 * 128; f += 512 * 4) {
        int node = tile * 64 + (f >> 7);
        float4 v = make_float4(0.f, 0.f, 0.f, 0.f);
        if (node < n) v = *(const float4*)(in + (size_t)tile * 8192 + f);
        *(float4*)(xs + f) = v;
    }
    __syncthreads();

    const int cg = t & 63;
    const int ng = t >> 6;
    const int c0 = cg * 4;
    const float* Wp = (c0 < 128) ? (Wl + c0) : (Wr + (c0 - 128));
    float* Op = (c0 < 128) ? xl : xr;
    const int co = c0 & 127;
    const float* xrow = xs + ng * 8 * 128;

    float4 acc[8];
#pragma unroll
    for (int i = 0; i < 8; i++) acc[i] = make_float4(0.f, 0.f, 0.f, 0.f);

    for (int k0 = 0; k0 < 128; k0 += 4) {
        float4 w0 = *(const float4*)(Wp + (size_t)(k0 + 0) * 128);
        float4 w1 = *(const float4*)(Wp + (size_t)(k0 + 1) * 128);
        float4 w2 = *(const float4*)(Wp + (size_t)(k0 + 2) * 128);
        float4 w3 = *(const float4*)(Wp + (size_t)(k0 + 3) * 128);
#pragma unroll
        for (int i = 0; i < 8; i++) {
            float4 xv = *(const float4*)(xrow + i * 128 + k0);
            acc[i].x = fmaf(xv.x, w0.x, acc[i].x);
            acc[i].y = fmaf(xv.x, w0.y, acc[i].y);
            acc[i].z = fmaf(xv.x, w0.z, acc[i].z);
            acc[i].w = fmaf(xv.x, w0.w, acc[i].w);
            acc[i].x = fmaf(xv.y, w1.x, acc[i].x);
            acc[i].y = fmaf(xv.y, w1.y, acc[i].y);
            acc[i].z = fmaf(xv.y, w1.z, acc[i].z);
            acc[i].w = fmaf(xv.y, w1.w, acc[i].w);
            acc[i].x = fmaf(xv.z, w2.x, acc[i].x);
            acc[i].y = fmaf(xv.z, w2.y, acc[i].y);
            acc[i].z = fmaf(xv.z, w2.z, acc[i].z);
            acc[i].w = fmaf(xv.z, w2.w, acc[i].w);
            acc[i].x = fmaf(xv.w, w3.x, acc[i].x);
            acc[i].y = fmaf(xv.w, w3.y, acc[i].y);
            acc[i].z = fmaf(xv.w, w3.z, acc[i].z);
            acc[i].w = fmaf(xv.w, w3.w, acc[i].w);
        }
    }

#pragma unroll
    for (int i = 0; i < 8; i++) {
        int node = tile * 64 + ng * 8 + i;
        if (node < n) *(float4*)(Op + (size_t)node * 128 + co) = acc[i];
    }
}

// ---------------------------------------------------------------------------
// CSR build (dst-sorted), once per call, reused by both layers.
// ---------------------------------------------------------------------------
__global__ __launch_bounds__(256) void k_deg_init(int* __restrict__ deg)
{
    int i = blockIdx.x * 256 + threadIdx.x;
    if (i < NN) deg[i] = 1;  // self-loop
}

__global__ __launch_bounds__(256) void k_hist(
    const int* __restrict__ ei, int* __restrict__ deg)
{
    int e = blockIdx.x * 256 + threadIdx.x;
    if (e < NE) atomicAdd(deg + ei[NE + e], 1);
}

__global__ __launch_bounds__(1024) void k_scan(
    const int* __restrict__ deg, int* __restrict__ rowptr)
{
    __shared__ int ps[1024];
    const int t = threadIdx.x;
    const int CH = 49;
    int lo = t * CH, hi = min(lo + CH, NN);
    int s = 0;
    for (int i = lo; i < hi; i++) s += deg[i];
    ps[t] = s;
    __syncthreads();
    for (int off = 1; off < 1024; off <<= 1) {
        int v = (t >= off) ? ps[t - off] : 0;
        __syncthreads();
        ps[t] += v;
        __syncthreads();
    }
    int base = (t == 0) ? 0 : ps[t - 1];
    for (int i = lo; i < hi; i++) { rowptr[i] = base; base += deg[i]; }
    if (t == 0) rowptr[NN] = NE + NN;
}

__global__ __launch_bounds__(256) void k_fill_self(
    const int* __restrict__ rowptr, int* __restrict__ nxt,
    int* __restrict__ esrc)
{
    int i = blockIdx.x * 256 + threadIdx.x;
    if (i >= NN) return;
    int r = rowptr[i];
    esrc[r] = i;
    nxt[i] = r + 1;
}

__global__ __launch_bounds__(256) void k_scatter(
    const int* __restrict__ ei, int* __restrict__ nxt,
    int* __restrict__ esrc)
{
    int e = blockIdx.x * 256 + threadIdx.x;
    if (e >= NE) return;
    int s = ei[e], d = ei[NE + e];
    int pos = atomicAdd(nxt + d, 1);
    esrc[pos] = s;
}

// ---------------------------------------------------------------------------
// Gather GAT row: half-wave (32 lanes x float4) per dst node.
// 4 edges per iteration, next group's rows prefetched -> 8 loads in flight.
// ---------------------------------------------------------------------------
__device__ __forceinline__ float4 ld_row(const float* __restrict__ xl,
                                         int s, int q)
{
    return *(const float4*)(xl + (size_t)s * 128 + q * 4);
}

__device__ __forceinline__ void gat_row(
    const float* __restrict__ xl, const float4 xr4, const float4 at,
    const int* __restrict__ esrc, int beg, int end, int q,
    float4& acc, float& den)
{
    acc = make_float4(0.f, 0.f, 0.f, 0.f);
    den = 0.f;
    const int last = end - 1;

    // prime group 0 (indices clamped; masked later)
    int s0 = esrc[beg];
    int s1 = esrc[min(beg + 1, last)];
    int s2 = esrc[min(beg + 2, last)];
    int s3 = esrc[min(beg + 3, last)];
    float4 a0 = ld_row(xl, s0, q);
    float4 a1 = ld_row(xl, s1, q);
    float4 a2 = ld_row(xl, s2, q);
    float4 a3 = ld_row(xl, s3, q);

    for (int i0 = beg; i0 < end; i0 += 4) {
        float4 c0 = a0, c1 = a1, c2 = a2, c3 = a3;
        int rem = end - i0;          // >= 1

        int nx = i0 + 4;
        if (nx < end) {              // prefetch next group
            s0 = esrc[nx];
            s1 = esrc[min(nx + 1, last)];
            s2 = esrc[min(nx + 2, last)];
            s3 = esrc[min(nx + 3, last)];
            a0 = ld_row(xl, s0, q);
            a1 = ld_row(xl, s1, q);
            a2 = ld_row(xl, s2, q);
            a3 = ld_row(xl, s3, q);
        }

#define LOGIT(c, e)                                                         \
        {                                                                   \
            float v0 = c.x + xr4.x; v0 = v0 > 0.f ? v0 : 0.2f * v0;         \
            float v1 = c.y + xr4.y; v1 = v1 > 0.f ? v1 : 0.2f * v1;         \
            float v2 = c.z + xr4.z; v2 = v2 > 0.f ? v2 : 0.2f * v2;         \
            float v3 = c.w + xr4.w; v3 = v3 > 0.f ? v3 : 0.2f * v3;         \
            e = v0 * at.x + v1 * at.y + v2 * at.z + v3 * at.w;              \
        }
        float e0, e1, e2, e3;
        LOGIT(c0, e0) LOGIT(c1, e1) LOGIT(c2, e2) LOGIT(c3, e3)
#undef LOGIT

#pragma unroll
        for (int off = 16; off; off >>= 1) {
            e0 += __shfl_xor(e0, off, 64);
            e1 += __shfl_xor(e1, off, 64);
            e2 += __shfl_xor(e2, off, 64);
            e3 += __shfl_xor(e3, off, 64);
        }

        float p0 = __expf(fminf(e0, 80.f));
        float p1 = (rem > 1) ? __expf(fminf(e1, 80.f)) : 0.f;
        float p2 = (rem > 2) ? __expf(fminf(e2, 80.f)) : 0.f;
        float p3 = (rem > 3) ? __expf(fminf(e3, 80.f)) : 0.f;

        den += (p0 + p1) + (p2 + p3);
        acc.x = fmaf(p0, c0.x, fmaf(p1, c1.x, fmaf(p2, c2.x, fmaf(p3, c3.x, acc.x))));
        acc.y = fmaf(p0, c0.y, fmaf(p1, c1.y, fmaf(p2, c2.y, fmaf(p3, c3.y, acc.y))));
        acc.z = fmaf(p0, c0.z, fmaf(p1, c1.z, fmaf(p2, c2.z, fmaf(p3, c3.z, acc.z))));
        acc.w = fmaf(p0, c0.w, fmaf(p1, c1.w, fmaf(p2, c2.w, fmaf(p3, c3.w, acc.w))));
    }
}

// layer1: fused normalize + bias + ReLU + LayerNorm -> h
__global__ __launch_bounds__(256) void k_gat1(
    const float* __restrict__ xl, const float* __restrict__ xr,
    const float* __restrict__ att, const int* __restrict__ rowptr,
    const int* __restrict__ esrc, const float* __restrict__ bias,
    const float* __restrict__ g_ln, const float* __restrict__ b_ln,
    float* __restrict__ h)
{
    int d = (int)((blockIdx.x * 256 + threadIdx.x) >> 5);
    int q = threadIdx.x & 31;
    if (d >= NN) return;

    float4 xr4 = *(const float4*)(xr + (size_t)d * 128 + q * 4);
    float4 at  = *(const float4*)(att + q * 4);
    float4 acc; float den;
    gat_row(xl, xr4, at, esrc, rowptr[d], rowptr[d + 1], q, acc, den);

    float inv = 1.f / (den + 1e-16f);
    float4 bb = *(const float4*)(bias + q * 4);
    float x0 = fmaxf(fmaf(acc.x, inv, bb.x), 0.f);
    float x1 = fmaxf(fmaf(acc.y, inv, bb.y), 0.f);
    float x2 = fmaxf(fmaf(acc.z, inv, bb.z), 0.f);
    float x3 = fmaxf(fmaf(acc.w, inv, bb.w), 0.f);

    float s1 = x0 + x1 + x2 + x3;
    float s2 = x0 * x0 + x1 * x1 + x2 * x2 + x3 * x3;
#pragma unroll
    for (int off = 16; off; off >>= 1) {
        s1 += __shfl_xor(s1, off, 64);
        s2 += __shfl_xor(s2, off, 64);
    }
    float mu = s1 * (1.f / 128.f);
    float var = s2 * (1.f / 128.f) - mu * mu;
    float rstd = rsqrtf(var + 1e-5f);

    float4 g  = *(const float4*)(g_ln + q * 4);
    float4 bl = *(const float4*)(b_ln + q * 4);
    float4 o;
    o.x = (x0 - mu) * rstd * g.x + bl.x;
    o.y = (x1 - mu) * rstd * g.y + bl.y;
    o.z = (x2 - mu) * rstd * g.z + bl.z;
    o.w = (x3 - mu) * rstd * g.w + bl.w;
    *(float4*)(h + (size_t)d * 128 + q * 4) = o;
}

// layer2: fused normalize + bias + mean-pool scatter
__global__ __launch_bounds__(256) void k_gat2(
    const float* __restrict__ xl, const float* __restrict__ xr,
    const float* __restrict__ att, const int* __restrict__ rowptr,
    const int* __restrict__ esrc, const float* __restrict__ bias,
    const int* __restrict__ batch, float* __restrict__ pooled,
    float* __restrict__ cnt)
{
    int d = (int)((blockIdx.x * 256 + threadIdx.x) >> 5);
    int q = threadIdx.x & 31;
    if (d >= NN) return;

    float4 xr4 = *(const float4*)(xr + (size_t)d * 128 + q * 4);
    float4 at  = *(const float4*)(att + q * 4);
    float4 acc; float den;
    gat_row(xl, xr4, at, esrc, rowptr[d], rowptr[d + 1], q, acc, den);

    float inv = 1.f / (den + 1e-16f);
    float4 bb = *(const float4*)(bias + q * 4);
    int g = batch[d];
    float* pp = pooled + (size_t)g * 128 + q * 4;
    atomicAdd(pp + 0, fmaf(acc.x, inv, bb.x));
    atomicAdd(pp + 1, fmaf(acc.y, inv, bb.y));
    atomicAdd(pp + 2, fmaf(acc.z, inv, bb.z));
    atomicAdd(pp + 3, fmaf(acc.w, inv, bb.w));
    if (q == 0) atomicAdd(cnt + g, 1.f);
}

// ---------------------------------------------------------------------------
__global__ __launch_bounds__(256) void k_linear(
    const float* __restrict__ pooled, const float* __restrict__ cnt,
    const float* __restrict__ W, const float* __restrict__ b,
    float* __restrict__ out)
{
    int idx = blockIdx.x * 256 + threadIdx.x;
    if (idx >= NG * NC) return;
    int g = idx / NC, c = idx % NC;
    float invc = 1.f / fmaxf(cnt[g], 1.f);
    float s = 0.f;
    for (int k = 0; k < HID; k++)
        s = fmaf(pooled[(size_t)g * 128 + k], W[(size_t)k * NC + c], s);
    out[idx] = fmaf(s, invc, b[c]);
}

// ---------------------------------------------------------------------------
extern "C" void kernel_launch(void* const* d_in, const int* in_sizes, int n_in,
                              void* d_out, int out_size, void* d_ws, size_t ws_size,
                              hipStream_t stream)
{
    const float* x     = (const float*)d_in[0];
    const int*   ei    = (const int*)d_in[1];
    const int*   batch = (const int*)d_in[2];
    const float* Wl1   = (const float*)d_in[3];
    const float* Wr1   = (const float*)d_in[4];
    const float* att1  = (const float*)d_in[5];
    const float* b1    = (const float*)d_in[6];
    const float* g_ln  = (const float*)d_in[7];
    const float* b_ln  = (const float*)d_in[8];
    const float* Wl2   = (const float*)d_in[9];
    const float* Wr2   = (const float*)d_in[10];
    const float* att2  = (const float*)d_in[11];
    const float* b2    = (const float*)d_in[12];
    const float* Wlin  = (const float*)d_in[13];
    const float* blin  = (const float*)d_in[14];
    float* out = (float*)d_out;

    float* ws = (float*)d_ws;
    float* xl     = ws;                           // 6.4M floats
    float* xr     = xl + (size_t)NN * HID;        // 6.4M
    float* h      = xr + (size_t)NN * HID;        // 6.4M
    float* pooled = h + (size_t)NN * HID;         // 32768
    float* cnt    = pooled + (size_t)NG * HID;    // 256
    int* deg    = (int*)(cnt + NG);               // NN
    int* rowptr = deg + NN;                       // NN+1
    int* nxt    = rowptr + NN + 1;                // NN
    int* esrc   = nxt + NN;                       // NE+NN

    const int node_blocks = (NN + 255) / 256;
    const int edge_blocks = (NE + 255) / 256;
    const int gemm_blocks = (NN + 63) / 64;
    const int gat_blocks  = (NN * 32 + 255) / 256;

    // ---- CSR build ----
    k_deg_init<<<node_blocks, 256, 0, stream>>>(deg);
    k_hist<<<edge_blocks, 256, 0, stream>>>(ei, deg);
    k_scan<<<1, 1024, 0, stream>>>(deg, rowptr);
    k_fill_self<<<node_blocks, 256, 0, stream>>>(rowptr, nxt, esrc);
    k_scatter<<<edge_blocks, 256, 0, stream>>>(ei, nxt, esrc);

    hipMemsetAsync(pooled, 0, ((size_t)NG * HID + NG) * sizeof(float), stream);

    // ---- layer 1 ----
    k_dual_gemm<<<gemm_blocks, 512, 0, stream>>>(x, Wl1, Wr1, xl, xr, NN);
    k_gat1<<<gat_blocks, 256, 0, stream>>>(xl, xr, att1, rowptr, esrc,
                                           b1, g_ln, b_ln, h);

    // ---- layer 2 ----
    k_dual_gemm<<<gemm_blocks, 512, 0, stream>>>(h, Wl2, Wr2, xl, xr, NN);
    k_gat2<<<gat_blocks, 256, 0, stream>>>(xl, xr, att2, rowptr, esrc,
                                           b2, batch, pooled, cnt);

    // ---- head ----
    k_linear<<<(NG * NC + 255) / 256, 256, 0, stream>>>(pooled, cnt, Wlin, blin, out);
}

// Round 4
// 565.811 us; speedup vs baseline: 3.2276x; 1.0545x over previous
//
#include <hip/hip_runtime.h>
#include <hip/hip_bf16.h>
#include <hip/hip_fp16.h>

#define NN 50000
#define NE 800000
#define HID 128
#define NG 256
#define NC 10

// fp16 row helpers: 4 halves packed in a uint2 (8 B)
__device__ __forceinline__ float4 h4tof4(uint2 r)
{
    __half2 a = *(__half2*)&r.x;
    __half2 b = *(__half2*)&r.y;
    float2 fa = __half22float2(a);
    float2 fb = __half22float2(b);
    return make_float4(fa.x, fa.y, fb.x, fb.y);
}

__device__ __forceinline__ uint2 f4toh4(float4 v)
{
    __half2 a = __floats2half2_rn(v.x, v.y);
    __half2 b = __floats2half2_rn(v.z, v.w);
    uint2 r;
    r.x = *(unsigned int*)&a;
    r.y = *(unsigned int*)&b;
    return r;
}

// ---------------------------------------------------------------------------
// dual GEMM: xlh = fp16(in @ Wl), xr = in @ Wr (f32).
// in:[n,128], W:[128,128] row-major. 64-node LDS tile, 512 threads.
// ---------------------------------------------------------------------------
__global__ __launch_bounds__(512) void k_dual_gemm(
    const float* __restrict__ in, const float* __restrict__ Wl,
    const float* __restrict__ Wr, uint2* __restrict__ xlh,
    float* __restrict__ xr, int n)
{
    __shared__ float xs[64 * 128];
    const int tile = blockIdx.x;
    const int t = threadIdx.x;

    for (int f = t * 4; f < 64 * 128; f += 512 * 4) {
        int node = tile * 64 + (f >> 7);
        float4 v = make_float4(0.f, 0.f, 0.f, 0.f);
        if (node < n) v = *(const float4*)(in + (size_t)tile * 8192 + f);
        *(float4*)(xs + f) = v;
    }
    __syncthreads();

    const int cg = t & 63;
    const int ng = t >> 6;
    const int c0 = cg * 4;
    const bool is_l = (c0 < 128);
    const float* Wp = is_l ? (Wl + c0) : (Wr + (c0 - 128));
    const int co = c0 & 127;
    const float* xrow = xs + ng * 8 * 128;

    float4 acc[8];
#pragma unroll
    for (int i = 0; i < 8; i++) acc[i] = make_float4(0.f, 0.f, 0.f, 0.f);

    for (int k0 = 0; k0 < 128; k0 += 4) {
        float4 w0 = *(const float4*)(Wp + (size_t)(k0 + 0) * 128);
        float4 w1 = *(const float4*)(Wp + (size_t)(k0 + 1) * 128);
        float4 w2 = *(const float4*)(Wp + (size_t)(k0 + 2) * 128);
        float4 w3 = *(const float4*)(Wp + (size_t)(k0 + 3) * 128);
#pragma unroll
        for (int i = 0; i < 8; i++) {
            float4 xv = *(const float4*)(xrow + i * 128 + k0);
            acc[i].x = fmaf(xv.x, w0.x, acc[i].x);
            acc[i].y = fmaf(xv.x, w0.y, acc[i].y);
            acc[i].z = fmaf(xv.x, w0.z, acc[i].z);
            acc[i].w = fmaf(xv.x, w0.w, acc[i].w);
            acc[i].x = fmaf(xv.y, w1.x, acc[i].x);
            acc[i].y = fmaf(xv.y, w1.y, acc[i].y);
            acc[i].z = fmaf(xv.y, w1.z, acc[i].z);
            acc[i].w = fmaf(xv.y, w1.w, acc[i].w);
            acc[i].x = fmaf(xv.z, w2.x, acc[i].x);
            acc[i].y = fmaf(xv.z, w2.y, acc[i].y);
            acc[i].z = fmaf(xv.z, w2.z, acc[i].z);
            acc[i].w = fmaf(xv.z, w2.w, acc[i].w);
            acc[i].x = fmaf(xv.w, w3.x, acc[i].x);
            acc[i].y = fmaf(xv.w, w3.y, acc[i].y);
            acc[i].z = fmaf(xv.w, w3.z, acc[i].z);
            acc[i].w = fmaf(xv.w, w3.w, acc[i].w);
        }
    }

#pragma unroll
    for (int i = 0; i < 8; i++) {
        int node = tile * 64 + ng * 8 + i;
        if (node >= n) continue;
        if (is_l)
            xlh[(size_t)node * 32 + (co >> 2)] = f4toh4(acc[i]);
        else
            *(float4*)(xr + (size_t)node * 128 + co) = acc[i];
    }
}

// ---------------------------------------------------------------------------
// CSR build (dst-sorted), once per call, reused by both layers.
// ---------------------------------------------------------------------------
__global__ __launch_bounds__(256) void k_deg_init(int* __restrict__ deg)
{
    int i = blockIdx.x * 256 + threadIdx.x;
    if (i < NN) deg[i] = 1;  // self-loop
}

__global__ __launch_bounds__(256) void k_hist(
    const int* __restrict__ ei, int* __restrict__ deg)
{
    int e = blockIdx.x * 256 + threadIdx.x;
    if (e < NE) atomicAdd(deg + ei[NE + e], 1);
}

__global__ __launch_bounds__(1024) void k_scan(
    const int* __restrict__ deg, int* __restrict__ rowptr)
{
    __shared__ int ps[1024];
    const int t = threadIdx.x;
    const int CH = 49;
    int lo = t * CH, hi = min(lo + CH, NN);
    int s = 0;
    for (int i = lo; i < hi; i++) s += deg[i];
    ps[t] = s;
    __syncthreads();
    for (int off = 1; off < 1024; off <<= 1) {
        int v = (t >= off) ? ps[t - off] : 0;
        __syncthreads();
        ps[t] += v;
        __syncthreads();
    }
    int base = (t == 0) ? 0 : ps[t - 1];
    for (int i = lo; i < hi; i++) { rowptr[i] = base; base += deg[i]; }
    if (t == 0) rowptr[NN] = NE + NN;
}

__global__ __launch_bounds__(256) void k_fill_self(
    const int* __restrict__ rowptr, int* __restrict__ nxt,
    int* __restrict__ esrc)
{
    int i = blockIdx.x * 256 + threadIdx.x;
    if (i >= NN) return;
    int r = rowptr[i];
    esrc[r] = i;
    nxt[i] = r + 1;
}

__global__ __launch_bounds__(256) void k_scatter(
    const int* __restrict__ ei, int* __restrict__ nxt,
    int* __restrict__ esrc)
{
    int e = blockIdx.x * 256 + threadIdx.x;
    if (e >= NE) return;
    int s = ei[e], d = ei[NE + e];
    int pos = atomicAdd(nxt + d, 1);
    esrc[pos] = s;
}

// ---------------------------------------------------------------------------
// Gather GAT row: half-wave (32 lanes x 4 halves = 128 feats) per dst node.
// 4 edges per iteration, next group prefetched (raw fp16 bits in regs).
// ---------------------------------------------------------------------------
__device__ __forceinline__ uint2 ld_rowh(const uint2* __restrict__ xlh,
                                         int s, int q)
{
    return xlh[(size_t)s * 32 + q];
}

__device__ __forceinline__ void gat_row(
    const uint2* __restrict__ xlh, const float4 xr4, const float4 at,
    const int* __restrict__ esrc, int beg, int end, int q,
    float4& acc, float& den)
{
    acc = make_float4(0.f, 0.f, 0.f, 0.f);
    den = 0.f;
    const int last = end - 1;

    int s0 = esrc[beg];
    int s1 = esrc[min(beg + 1, last)];
    int s2 = esrc[min(beg + 2, last)];
    int s3 = esrc[min(beg + 3, last)];
    uint2 r0 = ld_rowh(xlh, s0, q);
    uint2 r1 = ld_rowh(xlh, s1, q);
    uint2 r2 = ld_rowh(xlh, s2, q);
    uint2 r3 = ld_rowh(xlh, s3, q);

    for (int i0 = beg; i0 < end; i0 += 4) {
        float4 c0 = h4tof4(r0);
        float4 c1 = h4tof4(r1);
        float4 c2 = h4tof4(r2);
        float4 c3 = h4tof4(r3);
        int rem = end - i0;  // >= 1

        int nx = i0 + 4;
        if (nx < end) {
            s0 = esrc[nx];
            s1 = esrc[min(nx + 1, last)];
            s2 = esrc[min(nx + 2, last)];
            s3 = esrc[min(nx + 3, last)];
            r0 = ld_rowh(xlh, s0, q);
            r1 = ld_rowh(xlh, s1, q);
            r2 = ld_rowh(xlh, s2, q);
            r3 = ld_rowh(xlh, s3, q);
        }

#define LOGIT(c, e)                                                         \
        {                                                                   \
            float v0 = c.x + xr4.x; v0 = v0 > 0.f ? v0 : 0.2f * v0;         \
            float v1 = c.y + xr4.y; v1 = v1 > 0.f ? v1 : 0.2f * v1;         \
            float v2 = c.z + xr4.z; v2 = v2 > 0.f ? v2 : 0.2f * v2;         \
            float v3 = c.w + xr4.w; v3 = v3 > 0.f ? v3 : 0.2f * v3;         \
            e = v0 * at.x + v1 * at.y + v2 * at.z + v3 * at.w;              \
        }
        float e0, e1, e2, e3;
        LOGIT(c0, e0) LOGIT(c1, e1) LOGIT(c2, e2) LOGIT(c3, e3)
#undef LOGIT

#pragma unroll
        for (int off = 16; off; off >>= 1) {
            e0 += __shfl_xor(e0, off, 64);
            e1 += __shfl_xor(e1, off, 64);
            e2 += __shfl_xor(e2, off, 64);
            e3 += __shfl_xor(e3, off, 64);
        }

        float p0 = __expf(fminf(e0, 80.f));
        float p1 = (rem > 1) ? __expf(fminf(e1, 80.f)) : 0.f;
        float p2 = (rem > 2) ? __expf(fminf(e2, 80.f)) : 0.f;
        float p3 = (rem > 3) ? __expf(fminf(e3, 80.f)) : 0.f;

        den += (p0 + p1) + (p2 + p3);
        acc.x = fmaf(p0, c0.x, fmaf(p1, c1.x, fmaf(p2, c2.x, fmaf(p3, c3.x, acc.x))));
        acc.y = fmaf(p0, c0.y, fmaf(p1, c1.y, fmaf(p2, c2.y, fmaf(p3, c3.y, acc.y))));
        acc.z = fmaf(p0, c0.z, fmaf(p1, c1.z, fmaf(p2, c2.z, fmaf(p3, c3.z, acc.z))));
        acc.w = fmaf(p0, c0.w, fmaf(p1, c1.w, fmaf(p2, c2.w, fmaf(p3, c3.w, acc.w))));
    }
}

// layer1: fused normalize + bias + ReLU + LayerNorm -> h (f32)
__global__ __launch_bounds__(256) void k_gat1(
    const uint2* __restrict__ xlh, const float* __restrict__ xr,
    const float* __restrict__ att, const int* __restrict__ rowptr,
    const int* __restrict__ esrc, const float* __restrict__ bias,
    const float* __restrict__ g_ln, const float* __restrict__ b_ln,
    float* __restrict__ h)
{
    int d = (int)((blockIdx.x * 256 + threadIdx.x) >> 5);
    int q = threadIdx.x & 31;
    if (d >= NN) return;

    float4 xr4 = *(const float4*)(xr + (size_t)d * 128 + q * 4);
    float4 at  = *(const float4*)(att + q * 4);
    float4 acc; float den;
    gat_row(xlh, xr4, at, esrc, rowptr[d], rowptr[d + 1], q, acc, den);

    float inv = 1.f / (den + 1e-16f);
    float4 bb = *(const float4*)(bias + q * 4);
    float x0 = fmaxf(fmaf(acc.x, inv, bb.x), 0.f);
    float x1 = fmaxf(fmaf(acc.y, inv, bb.y), 0.f);
    float x2 = fmaxf(fmaf(acc.z, inv, bb.z), 0.f);
    float x3 = fmaxf(fmaf(acc.w, inv, bb.w), 0.f);

    float s1 = x0 + x1 + x2 + x3;
    float s2 = x0 * x0 + x1 * x1 + x2 * x2 + x3 * x3;
#pragma unroll
    for (int off = 16; off; off >>= 1) {
        s1 += __shfl_xor(s1, off, 64);
        s2 += __shfl_xor(s2, off, 64);
    }
    float mu = s1 * (1.f / 128.f);
    float var = s2 * (1.f / 128.f) - mu * mu;
    float rstd = rsqrtf(var + 1e-5f);

    float4 g  = *(const float4*)(g_ln + q * 4);
    float4 bl = *(const float4*)(b_ln + q * 4);
    float4 o;
    o.x = (x0 - mu) * rstd * g.x + bl.x;
    o.y = (x1 - mu) * rstd * g.y + bl.y;
    o.z = (x2 - mu) * rstd * g.z + bl.z;
    o.w = (x3 - mu) * rstd * g.w + bl.w;
    *(float4*)(h + (size_t)d * 128 + q * 4) = o;
}

// layer2: fused normalize + bias + mean-pool scatter
__global__ __launch_bounds__(256) void k_gat2(
    const uint2* __restrict__ xlh, const float* __restrict__ xr,
    const float* __restrict__ att, const int* __restrict__ rowptr,
    const int* __restrict__ esrc, const float* __restrict__ bias,
    const int* __restrict__ batch, float* __restrict__ pooled,
    float* __restrict__ cnt)
{
    int d = (int)((blockIdx.x * 256 + threadIdx.x) >> 5);
    int q = threadIdx.x & 31;
    if (d >= NN) return;

    float4 xr4 = *(const float4*)(xr + (size_t)d * 128 + q * 4);
    float4 at  = *(const float4*)(att + q * 4);
    float4 acc; float den;
    gat_row(xlh, xr4, at, esrc, rowptr[d], rowptr[d + 1], q, acc, den);

    float inv = 1.f / (den + 1e-16f);
    float4 bb = *(const float4*)(bias + q * 4);
    int g = batch[d];
    float* pp = pooled + (size_t)g * 128 + q * 4;
    atomicAdd(pp + 0, fmaf(acc.x, inv, bb.x));
    atomicAdd(pp + 1, fmaf(acc.y, inv, bb.y));
    atomicAdd(pp + 2, fmaf(acc.z, inv, bb.z));
    atomicAdd(pp + 3, fmaf(acc.w, inv, bb.w));
    if (q == 0) atomicAdd(cnt + g, 1.f);
}

// ---------------------------------------------------------------------------
__global__ __launch_bounds__(256) void k_linear(
    const float* __restrict__ pooled, const float* __restrict__ cnt,
    const float* __restrict__ W, const float* __restrict__ b,
    float* __restrict__ out)
{
    int idx = blockIdx.x * 256 + threadIdx.x;
    if (idx >= NG * NC) return;
    int g = idx / NC, c = idx % NC;
    float invc = 1.f / fmaxf(cnt[g], 1.f);
    float s = 0.f;
    for (int k = 0; k < HID; k++)
        s = fmaf(pooled[(size_t)g * 128 + k], W[(size_t)k * NC + c], s);
    out[idx] = fmaf(s, invc, b[c]);
}

// ---------------------------------------------------------------------------
extern "C" void kernel_launch(void* const* d_in, const int* in_sizes, int n_in,
                              void* d_out, int out_size, void* d_ws, size_t ws_size,
                              hipStream_t stream)
{
    const float* x     = (const float*)d_in[0];
    const int*   ei    = (const int*)d_in[1];
    const int*   batch = (const int*)d_in[2];
    const float* Wl1   = (const float*)d_in[3];
    const float* Wr1   = (const float*)d_in[4];
    const float* att1  = (const float*)d_in[5];
    const float* b1    = (const float*)d_in[6];
    const float* g_ln  = (const float*)d_in[7];
    const float* b_ln  = (const float*)d_in[8];
    const float* Wl2   = (const float*)d_in[9];
    const float* Wr2   = (const float*)d_in[10];
    const float* att2  = (const float*)d_in[11];
    const float* b2    = (const float*)d_in[12];
    const float* Wlin  = (const float*)d_in[13];
    const float* blin  = (const float*)d_in[14];
    float* out = (float*)d_out;

    char* ws = (char*)d_ws;
    uint2* xlh   = (uint2*)ws;                            // NN*32 uint2 = 12.8 MB
    float* xr    = (float*)(ws + (size_t)NN * 256);       // 25.6 MB
    float* h     = xr + (size_t)NN * HID;                 // 25.6 MB
    float* pooled = h + (size_t)NN * HID;                 // 128 KB
    float* cnt   = pooled + (size_t)NG * HID;             // 1 KB
    int* deg    = (int*)(cnt + NG);
    int* rowptr = deg + NN;
    int* nxt    = rowptr + NN + 1;
    int* esrc   = nxt + NN;                               // NE+NN

    const int node_blocks = (NN + 255) / 256;
    const int edge_blocks = (NE + 255) / 256;
    const int gemm_blocks = (NN + 63) / 64;
    const int gat_blocks  = (NN * 32 + 255) / 256;

    // ---- CSR build ----
    k_deg_init<<<node_blocks, 256, 0, stream>>>(deg);
    k_hist<<<edge_blocks, 256, 0, stream>>>(ei, deg);
    k_scan<<<1, 1024, 0, stream>>>(deg, rowptr);
    k_fill_self<<<node_blocks, 256, 0, stream>>>(rowptr, nxt, esrc);
    k_scatter<<<edge_blocks, 256, 0, stream>>>(ei, nxt, esrc);

    hipMemsetAsync(pooled, 0, ((size_t)NG * HID + NG) * sizeof(float), stream);

    // ---- layer 1 ----
    k_dual_gemm<<<gemm_blocks, 512, 0, stream>>>(x, Wl1, Wr1, xlh, xr, NN);
    k_gat1<<<gat_blocks, 256, 0, stream>>>(xlh, xr, att1, rowptr, esrc,
                                           b1, g_ln, b_ln, h);

    // ---- layer 2 ----
    k_dual_gemm<<<gemm_blocks, 512, 0, stream>>>(h, Wl2, Wr2, xlh, xr, NN);
    k_gat2<<<gat_blocks, 256, 0, stream>>>(xlh, xr, att2, rowptr, esrc,
                                           b2, batch, pooled, cnt);

    // ---- head ----
    k_linear<<<(NG * NC + 255) / 256, 256, 0, stream>>>(pooled, cnt, Wlin, blin, out);
}